// Round 3
// baseline (2551.687 us; speedup 1.0000x reference)
//
#include <hip/hip_runtime.h>
#include <math.h>

typedef unsigned short u16;
typedef unsigned int u32;
typedef __bf16 bf16x8 __attribute__((ext_vector_type(8)));
typedef float f32x4 __attribute__((ext_vector_type(4)));
typedef u16 us8 __attribute__((ext_vector_type(8)));

#define TOKENS 1024
#define DIM 256
#define SEQ 512

// ---------- helpers ----------

__device__ __forceinline__ u16 f2bf(float f) {
  u32 x = __float_as_uint(f);
  x += 0x7fffu + ((x >> 16) & 1u);
  return (u16)(x >> 16);
}

// silu + 8 cubic B-spline bases (uniform extended grid g[j] = (j-3)*0.4f - 1.0f)
__device__ __forceinline__ void expand9(float x, u16* sil, us8* u) {
  float sig = 1.0f / (1.0f + expf(-x));
  *sil = f2bf(x * sig);
  float bs[11];
#pragma unroll
  for (int j = 0; j < 11; j++) {
    float gj  = (float)(j - 3) * 0.4f - 1.0f;
    float gj1 = (float)(j - 2) * 0.4f - 1.0f;
    bs[j] = (x >= gj && x < gj1) ? 1.0f : 0.0f;
  }
#pragma unroll
  for (int k = 1; k <= 3; k++) {
#pragma unroll
    for (int j = 0; j < 10; j++) {
      if (j + k < 11) {
        float gj   = (float)(j - 3) * 0.4f - 1.0f;
        float gj1  = (float)(j - 2) * 0.4f - 1.0f;
        float gjk  = (float)(j + k - 3) * 0.4f - 1.0f;
        float gjk1 = (float)(j + k - 2) * 0.4f - 1.0f;
        bs[j] = (x - gj) / (gjk - gj) * bs[j] + (gjk1 - x) / (gjk1 - gj1) * bs[j + 1];
      }
    }
  }
#pragma unroll
  for (int c = 0; c < 8; c++) (*u)[c] = f2bf(bs[c]);
}

// 256-thread block sum (4 waves of 64)
__device__ __forceinline__ float block_sum_256(float v) {
  __shared__ float red[4];
  int t = threadIdx.x, lane = t & 63, wid = t >> 6;
#pragma unroll
  for (int o = 32; o > 0; o >>= 1) v += __shfl_down(v, o, 64);
  __syncthreads();
  if (lane == 0) red[wid] = v;
  __syncthreads();
  return red[0] + red[1] + red[2] + red[3];
}

// ---------- embedding + LN (eps 1e-12) + expand ----------

__global__ void embed_ln_x(const int* __restrict__ ids, const float* __restrict__ wemb,
                           const float* __restrict__ tt, const float* __restrict__ pe,
                           const float* __restrict__ g, const float* __restrict__ bta,
                           float* __restrict__ xout, u16* __restrict__ Xe) {
  int row = blockIdx.x, t = threadIdx.x;
  int id = ids[row];
  float v = wemb[(size_t)id * DIM + t] + tt[DIM + t] + pe[DIM + t];
  float mu = block_sum_256(v) * (1.0f / 256.0f);
  float d = v - mu;
  float var = block_sum_256(d * d) * (1.0f / 256.0f);
  float y = d * rsqrtf(var + 1e-12f) * g[t] + bta[t];
  xout[(size_t)row * DIM + t] = y;
  size_t base = (size_t)row * 2304;
  u16 s; us8 u;
  expand9(y, &s, &u);
  Xe[base + t] = s;
  *(us8*)(Xe + base + 256 + (size_t)t * 8) = u;
}

// ---------- (sum of nsum partials) [+gelu] [+res] + LN + expand ----------

__global__ void add_ln_x(const float* __restrict__ a, int nsum, int sstride,
                         const float* __restrict__ res,
                         const float* __restrict__ g, const float* __restrict__ bta,
                         float eps, int dogelu,
                         float* __restrict__ xout, u16* __restrict__ Xe) {
  int row = blockIdx.x, t = threadIdx.x;
  int idx = row * 256 + t;
  float v = 0.f;
  for (int s = 0; s < nsum; s++) v += a[(size_t)s * sstride + idx];
  if (dogelu) v = 0.5f * v * (1.0f + erff(v * 0.70710678118654752f));
  if (res) v += res[idx];
  float mu = block_sum_256(v) * (1.0f / 256.0f);
  float d = v - mu;
  float var = block_sum_256(d * d) * (1.0f / 256.0f);
  float y = d * rsqrtf(var + eps);
  if (g) y = y * g[t] + bta[t];
  xout[idx] = y;
  size_t base = (size_t)row * 2304;
  u16 s16; us8 u;
  expand9(y, &s16, &u);
  Xe[base + t] = s16;
  *(us8*)(Xe + base + 256 + (size_t)t * 8) = u;
}

// ---------- weight pack: [base | spline] f32 -> contiguous bf16 [rows x infeat*9] ----------

__global__ void pack_w(const float* __restrict__ base, const float* __restrict__ spl,
                       u16* __restrict__ dst, int shift, int nrows) {
  long idx = (long)blockIdx.x * 256 + threadIdx.x;
  if (idx >= ((long)nrows << shift)) return;
  int infeat = 1 << shift;
  long r = idx >> shift;
  int i = (int)(idx & (infeat - 1));
  int K = infeat * 9;
  dst[(size_t)r * K + i] = f2bf(base[idx]);
  const float* sp = spl + (size_t)idx * 8;
  float4 f0 = *(const float4*)sp;
  float4 f1v = *(const float4*)(sp + 4);
  us8 u;
  u[0] = f2bf(f0.x); u[1] = f2bf(f0.y); u[2] = f2bf(f0.z); u[3] = f2bf(f0.w);
  u[4] = f2bf(f1v.x); u[5] = f2bf(f1v.y); u[6] = f2bf(f1v.z); u[7] = f2bf(f1v.w);
  *(us8*)(dst + (size_t)r * K + infeat + (size_t)i * 8) = u;
}

// ---------- GEMM (packed bf16 weights): C[1024,N] = A[1024,K] @ W[N,K]^T ----------
// XCD-contiguous remap, XOR-swizzled LDS, register-prefetch pipeline.
// blockIdx.z = K-split slice (kchunk columns each); partial C at z*TOKENS*N.
// EPI: 0 = f32 store; 1 = relu + KAN-expand into XeOut (ld = infOut*9).

template <int BM, int BN, int EPI>
__global__ __launch_bounds__(256)
void gemm_b16(const u16* __restrict__ A,
              const u16* __restrict__ W0, const u16* __restrict__ W1, const u16* __restrict__ W2,
              int nper, int N, int K, int kchunk,
              float* __restrict__ C, u16* __restrict__ XeOut, int infOut) {
  constexpr int BK = 64;
  constexpr int FM = BM / 32, FN = BN / 32;
  constexpr int NA = BM / 32, NB = BN / 32;
  __shared__ u16 As[BM * BK];
  __shared__ u16 Bs[BN * BK];
  const int gx = gridDim.x;
  const int nwg = gx * gridDim.y;
  int g = blockIdx.y * gx + blockIdx.x;
  int lin = g;
  if ((nwg & 7) == 0) lin = (g & 7) * (nwg >> 3) + (g >> 3);
  const int m0 = (lin % gx) * BM;
  const int n0 = (lin / gx) * BN;
  const int z = blockIdx.z;
  const int kbeg = z * kchunk;
  const int kend = (kbeg + kchunk < K) ? kbeg + kchunk : K;
  const int t = threadIdx.x;
  const int lane = t & 63, wid = t >> 6;
  const int wm = (wid >> 1) * (BM / 2), wn = (wid & 1) * (BN / 2);
  const int proj = n0 / nper;
  const u16* W = proj == 0 ? W0 : (proj == 1 ? W1 : W2);
  const int onb = n0 - proj * nper;

  f32x4 acc[FM][FN];
#pragma unroll
  for (int i = 0; i < FM; i++)
#pragma unroll
    for (int j = 0; j < FN; j++) acc[i][j] = (f32x4){0.f, 0.f, 0.f, 0.f};

  const int frow = lane & 15;
  const int cgrp = lane >> 4;

  uint4 ra[NA], rb[NB];
  auto ldg = [&](int k0) {
#pragma unroll
    for (int c = 0; c < NA; c++) {
      int e = c * 256 + t, r = e >> 3, ch = e & 7;
      ra[c] = *(const uint4*)(A + (size_t)(m0 + r) * K + k0 + ch * 8);
    }
#pragma unroll
    for (int c = 0; c < NB; c++) {
      int e = c * 256 + t, r = e >> 3, ch = e & 7;
      rb[c] = *(const uint4*)(W + (size_t)(onb + r) * K + k0 + ch * 8);
    }
  };

  ldg(kbeg);
  for (int k0 = kbeg; k0 < kend; k0 += BK) {
#pragma unroll
    for (int c = 0; c < NA; c++) {
      int e = c * 256 + t, r = e >> 3, ch = e & 7;
      *(uint4*)(&As[r * BK + ((ch ^ (r & 7)) << 3)]) = ra[c];
    }
#pragma unroll
    for (int c = 0; c < NB; c++) {
      int e = c * 256 + t, r = e >> 3, ch = e & 7;
      *(uint4*)(&Bs[r * BK + ((ch ^ (r & 7)) << 3)]) = rb[c];
    }
    __syncthreads();
    if (k0 + BK < kend) ldg(k0 + BK);          // prefetch next tile (hides HBM latency)
#pragma unroll
    for (int half = 0; half < 2; half++) {
      const int ch = half * 4 + cgrp;
      bf16x8 af[FM], bfr[FN];
#pragma unroll
      for (int i = 0; i < FM; i++) {
        int rr = wm + i * 16 + frow;
        af[i] = *reinterpret_cast<const bf16x8*>(&As[rr * BK + ((ch ^ (rr & 7)) << 3)]);
      }
#pragma unroll
      for (int j = 0; j < FN; j++) {
        int rr = wn + j * 16 + frow;
        bfr[j] = *reinterpret_cast<const bf16x8*>(&Bs[rr * BK + ((ch ^ (rr & 7)) << 3)]);
      }
#pragma unroll
      for (int i = 0; i < FM; i++)
#pragma unroll
        for (int j = 0; j < FN; j++)
          acc[i][j] = __builtin_amdgcn_mfma_f32_16x16x32_bf16(af[i], bfr[j], acc[i][j], 0, 0, 0);
    }
    __syncthreads();
  }

  const int crow = (lane >> 4) * 4;
  const int ccol = lane & 15;
  if (EPI == 0) {
    float* Cz = C + (size_t)z * TOKENS * N;
#pragma unroll
    for (int i = 0; i < FM; i++)
#pragma unroll
      for (int j = 0; j < FN; j++) {
        int row = m0 + wm + i * 16 + crow;
        int col = n0 + wn + j * 16 + ccol;
#pragma unroll
        for (int r = 0; r < 4; r++)
          Cz[(size_t)(row + r) * N + col] = acc[i][j][r];
      }
  } else {
    const int ldXe = infOut * 9;
#pragma unroll
    for (int i = 0; i < FM; i++)
#pragma unroll
      for (int j = 0; j < FN; j++) {
        int row0 = m0 + wm + i * 16 + crow;
        int col = n0 + wn + j * 16 + ccol;
#pragma unroll
        for (int r = 0; r < 4; r++) {
          float y = fmaxf(acc[i][j][r], 0.0f);     // relu
          u16 s; us8 u;
          expand9(y, &s, &u);
          size_t base = (size_t)(row0 + r) * ldXe;
          XeOut[base + col] = s;
          *(us8*)(XeOut + base + infOut + (size_t)col * 8) = u;
        }
      }
  }
}

// ---------- attention: scores + softmax ----------

__global__ void attn_scores(const float* __restrict__ qkv, float* __restrict__ P) {
  int bh = blockIdx.x;
  int b = bh >> 2, h = bh & 3;
  int s0 = blockIdx.y * 16;
  int t = threadIdx.x;
  __shared__ float Qs[16][64];
  __shared__ float Ks[16][65];
  __shared__ float Ss[16][513];
  __shared__ float red[16][17];
#pragma unroll
  for (int c = 0; c < 4; c++) {
    int e = c * 256 + t, r = e >> 6, d = e & 63;
    Qs[r][d] = qkv[(size_t)(b * SEQ + s0 + r) * 768 + h * 64 + d];
  }
  int r = t >> 4, cc = t & 15;
  for (int kc = 0; kc < SEQ; kc += 16) {
    __syncthreads();
#pragma unroll
    for (int c = 0; c < 4; c++) {
      int e = c * 256 + t, rr = e >> 6, d = e & 63;
      Ks[rr][d] = qkv[(size_t)(b * SEQ + kc + rr) * 768 + 256 + h * 64 + d];
    }
    __syncthreads();
    float acc = 0.f;
#pragma unroll
    for (int d = 0; d < 64; d++) acc += Qs[r][d] * Ks[cc][d];
    Ss[r][kc + cc] = acc * 0.125f;
  }
  __syncthreads();
  float mx = -3.4e38f;
  for (int j = cc; j < SEQ; j += 16) mx = fmaxf(mx, Ss[r][j]);
  red[r][cc] = mx;
  __syncthreads();
  if (cc == 0) {
    float m = red[r][0];
#pragma unroll
    for (int j = 1; j < 16; j++) m = fmaxf(m, red[r][j]);
    red[r][16] = m;
  }
  __syncthreads();
  mx = red[r][16];
  float sm = 0.f;
  for (int j = cc; j < SEQ; j += 16) {
    float e = expf(Ss[r][j] - mx);
    Ss[r][j] = e;
    sm += e;
  }
  __syncthreads();
  red[r][cc] = sm;
  __syncthreads();
  if (cc == 0) {
    float s = 0.f;
#pragma unroll
    for (int j = 0; j < 16; j++) s += red[r][j];
    red[r][16] = s;
  }
  __syncthreads();
  float inv = 1.0f / red[r][16];
  float* prow = P + (size_t)(bh * SEQ + s0 + r) * SEQ;
  for (int j = cc; j < SEQ; j += 16) prow[j] = Ss[r][j] * inv;
}

// ---------- attention: ctx = P @ V, fused KAN-expand into Xe ----------

__global__ void attn_ctx_x(const float* __restrict__ qkv, const float* __restrict__ P,
                           u16* __restrict__ Xe) {
  int bh = blockIdx.x, b = bh >> 2, h = bh & 3;
  int s0 = blockIdx.y * 16;
  int t = threadIdx.x;
  __shared__ float Ps[16][513];
  __shared__ float Vs[32][65];
#pragma unroll
  for (int c = 0; c < 32; c++) {
    int e = c * 256 + t, r = e >> 9, j = e & 511;
    Ps[r][j] = P[(size_t)(bh * SEQ + s0 + r) * SEQ + j];
  }
  int r = t >> 4, dd = (t & 15) * 4;
  float a[4] = {0.f, 0.f, 0.f, 0.f};
  for (int kc = 0; kc < SEQ; kc += 32) {
    __syncthreads();
#pragma unroll
    for (int c = 0; c < 8; c++) {
      int e = c * 256 + t, rr = e >> 6, d = e & 63;
      Vs[rr][d] = qkv[(size_t)(b * SEQ + kc + rr) * 768 + 512 + h * 64 + d];
    }
    __syncthreads();
#pragma unroll
    for (int kk = 0; kk < 32; kk++) {
      float p = Ps[r][kc + kk];
      a[0] += p * Vs[kk][dd + 0];
      a[1] += p * Vs[kk][dd + 1];
      a[2] += p * Vs[kk][dd + 2];
      a[3] += p * Vs[kk][dd + 3];
    }
  }
  int row = b * SEQ + s0 + r;
  size_t base = (size_t)row * 2304;
#pragma unroll
  for (int j = 0; j < 4; j++) {
    int col = h * 64 + dd + j;
    u16 s; us8 u;
    expand9(a[j], &s, &u);
    Xe[base + col] = s;
    *(us8*)(Xe + base + 256 + (size_t)col * 8) = u;
  }
}

// ---------- launch ----------

extern "C" void kernel_launch(void* const* d_in, const int* in_sizes, int n_in,
                              void* d_out, int out_size, void* d_ws, size_t ws_size,
                              hipStream_t stream) {
  const int* ids = (const int*)d_in[0];
  const float* wemb = (const float*)d_in[1];
  const float* ttemb = (const float*)d_in[2];
  const float* pemb = (const float*)d_in[3];
  const float* elg = (const float*)d_in[4];
  const float* elb = (const float*)d_in[5];
  const float* qb = (const float*)d_in[6], *qs = (const float*)d_in[7];
  const float* kb = (const float*)d_in[8], *ks = (const float*)d_in[9];
  const float* vb = (const float*)d_in[10], *vs = (const float*)d_in[11];
  const float* ob = (const float*)d_in[12], *osp = (const float*)d_in[13];
  const float* f1b = (const float*)d_in[14], *f1s = (const float*)d_in[15];
  const float* f2b = (const float*)d_in[16], *f2s = (const float*)d_in[17];
  const float* l1g = (const float*)d_in[18], *l1b = (const float*)d_in[19];
  const float* l2g = (const float*)d_in[20], *l2b = (const float*)d_in[21];
  const float* hkb = (const float*)d_in[22], *hks = (const float*)d_in[23];
  const float* hob = (const float*)d_in[24], *hos = (const float*)d_in[25];
  float* out = (float*)d_out;

  char* w = (char*)d_ws;
  const size_t MB = 1 << 20;
  float* xbuf = (float*)(w);                 // 1 MB  [1024*256]
  float* tmp  = (float*)(w + 1 * MB);        // 1 MB
  float* qkv  = (float*)(w + 2 * MB);        // 3 MB  [1024*768]
  float* part = (float*)(w + 5 * MB);        // 4 MB  [4][1024*256] f2 split-K partials
  float* P    = (float*)(w + 10 * MB);       // 8 MB  [8*512*512]   (liveness-shares with Xe2)
  u16*   Xe2  = (u16*)  (w + 10 * MB);       // 18 MB [1024*9216]   f1-out expansion
  u16*   Xe   = (u16*)  (w + 28 * MB);       // 4.5MB [1024*2304]
  u16*   Wc   = (u16*)  (w + 33 * MB);       // 196 MB packed bf16 weights

  const size_t oq = 0, okk = 2359296, ov = 4718592, oo = 7077888;
  const size_t of1 = 9437184, of2 = 18874368, ohk = 28311552, oho = 28901376;

  pack_w<<<1024, 256, 0, stream>>>(qb, qs, Wc + oq, 8, 1024);
  pack_w<<<1024, 256, 0, stream>>>(kb, ks, Wc + okk, 8, 1024);
  pack_w<<<1024, 256, 0, stream>>>(vb, vs, Wc + ov, 8, 1024);
  pack_w<<<1024, 256, 0, stream>>>(ob, osp, Wc + oo, 8, 1024);
  pack_w<<<4096, 256, 0, stream>>>(f1b, f1s, Wc + of1, 8, 4096);
  pack_w<<<4096, 256, 0, stream>>>(f2b, f2s, Wc + of2, 10, 1024);
  pack_w<<<256, 256, 0, stream>>>(hkb, hks, Wc + ohk, 8, 256);
  pack_w<<<32000, 256, 0, stream>>>(hob, hos, Wc + oho, 8, 32000);

  embed_ln_x<<<TOKENS, 256, 0, stream>>>(ids, wemb, ttemb, pemb, elg, elb, xbuf, Xe);

  for (int l = 0; l < 4; l++) {
    const size_t wl = (size_t)l * 589824, fl = (size_t)l * 2359296;

    gemm_b16<32, 64, 0><<<dim3(32, 12), 256, 0, stream>>>(
        Xe, Wc + oq + wl, Wc + okk + wl, Wc + ov + wl, 256, 768, 2304, 2304,
        qkv, nullptr, 0);
    attn_scores<<<dim3(8, 32), 256, 0, stream>>>(qkv, P);
    attn_ctx_x<<<dim3(8, 32), 256, 0, stream>>>(qkv, P, Xe);
    gemm_b16<32, 32, 0><<<dim3(32, 8), 256, 0, stream>>>(
        Xe, Wc + oo + wl, Wc + oo + wl, Wc + oo + wl, 256, 256, 2304, 2304,
        tmp, nullptr, 0);
    add_ln_x<<<TOKENS, 256, 0, stream>>>(tmp, 1, 0, xbuf, l1g + l * 256, l1b + l * 256,
                                         1e-5f, 0, xbuf, Xe);
    gemm_b16<32, 64, 1><<<dim3(32, 16), 256, 0, stream>>>(
        Xe, Wc + of1 + fl, Wc + of1 + fl, Wc + of1 + fl, 1024, 1024, 2304, 2304,
        tmp, Xe2, 1024);
    gemm_b16<32, 32, 0><<<dim3(32, 8, 4), 256, 0, stream>>>(
        Xe2, Wc + of2 + fl, Wc + of2 + fl, Wc + of2 + fl, 256, 256, 9216, 2304,
        part, nullptr, 0);
    add_ln_x<<<TOKENS, 256, 0, stream>>>(part, 4, TOKENS * 256, xbuf,
                                         l2g + l * 256, l2b + l * 256, 1e-5f, 0, xbuf, Xe);
  }

  // head: KAN -> gelu -> LN(no affine, eps 1e-12) -> KAN to vocab
  gemm_b16<32, 32, 0><<<dim3(32, 8), 256, 0, stream>>>(
      Xe, Wc + ohk, Wc + ohk, Wc + ohk, 256, 256, 2304, 2304, tmp, nullptr, 0);
  add_ln_x<<<TOKENS, 256, 0, stream>>>(tmp, 1, 0, nullptr, nullptr, nullptr,
                                       1e-12f, 1, tmp, Xe);
  gemm_b16<128, 128, 0><<<dim3(8, 250), 256, 0, stream>>>(
      Xe, Wc + oho, Wc + oho, Wc + oho, 32000, 32000, 2304, 2304, out, nullptr, 0);
}